// Round 5
// baseline (3189.906 us; speedup 1.0000x reference)
//
#include <hip/hip_runtime.h>

typedef unsigned short u16;
typedef unsigned int   u32;
typedef __attribute__((ext_vector_type(4))) float  f32x4;
typedef __attribute__((ext_vector_type(8))) __bf16 bf16x8;
typedef __attribute__((ext_vector_type(8))) short  s16x8;
typedef __attribute__((ext_vector_type(4))) unsigned short u16x4;

#define DEVFN __device__ __forceinline__

DEVFN float bf2f(u16 u) {
    u32 v = ((u32)u) << 16;
    return __builtin_bit_cast(float, v);
}
DEVFN u16 f2bf(float f) {   // round-to-nearest-even
    u32 u = __builtin_bit_cast(u32, f);
    u32 r = u + 0x7FFFu + ((u >> 16) & 1u);
    return (u16)(r >> 16);
}

// async global->LDS, 16B per lane. LDS dest must be linear in lane order.
DEVFN void gload16(const void* g, void* l) {
    __builtin_amdgcn_global_load_lds(
        (const __attribute__((address_space(1))) void*)g,
        (__attribute__((address_space(3))) void*)l, 16, 0, 0);
}

// ---------------- embedding
__global__ __launch_bounds__(256) void embed_k(const int* __restrict__ idx,
                                               const float* __restrict__ tok,
                                               const float* __restrict__ pos,
                                               float* __restrict__ x)
{
    int i   = blockIdx.x * 256 + threadIdx.x;
    int row = i >> 8;
    int c   = (i & 255) << 2;
    int t   = row & 1023;
    int tk  = idx[row];
    float4 a = *(const float4*)&tok[(size_t)tk * 1024 + c];
    float4 p = *(const float4*)&pos[(size_t)t * 1024 + c];
    float4 r; r.x = a.x + p.x; r.y = a.y + p.y; r.z = a.z + p.z; r.w = a.w + p.w;
    *(float4*)&x[(size_t)row * 1024 + c] = r;
}

// ---------------- fp32 [K,N] -> bf16 [N,K] transpose (weights)
__global__ __launch_bounds__(256) void transpose_k(const float* __restrict__ W,
                                                   u16* __restrict__ Wt, int K, int N)
{
    __shared__ float tile[32][33];
    int n0 = blockIdx.x * 32, k0 = blockIdx.y * 32;
    int xx = threadIdx.x, ty = threadIdx.y;      // block (32,8)
#pragma unroll
    for (int yy = 0; yy < 4; ++yy) {
        int y = ty + yy * 8;
        tile[y][xx] = W[(size_t)(k0 + y) * N + n0 + xx];
    }
    __syncthreads();
#pragma unroll
    for (int yy = 0; yy < 4; ++yy) {
        int y = ty + yy * 8;
        Wt[(size_t)(n0 + y) * K + k0 + xx] = f2bf(tile[xx][y]);
    }
}

// ---------------- LayerNorm: fp32 in -> bf16 out, C=1024, one block per row
__global__ __launch_bounds__(256) void ln_k(const float* __restrict__ x,
                                            const float* __restrict__ g,
                                            const float* __restrict__ b,
                                            u16* __restrict__ out)
{
    const int row = blockIdx.x, tid = threadIdx.x;
    const float4 v = *(const float4*)&x[(size_t)row * 1024 + tid * 4];
    __shared__ float red[8];
    float s = v.x + v.y + v.z + v.w;
#pragma unroll
    for (int off = 32; off > 0; off >>= 1) s += __shfl_down(s, off);
    const int lane = tid & 63, wv = tid >> 6;
    if (lane == 0) red[wv] = s;
    __syncthreads();
    const float mu = (red[0] + red[1] + red[2] + red[3]) * (1.0f / 1024.0f);
    const float dx = v.x - mu, dy = v.y - mu, dz = v.z - mu, dw = v.w - mu;
    float s2 = dx * dx + dy * dy + dz * dz + dw * dw;
#pragma unroll
    for (int off = 32; off > 0; off >>= 1) s2 += __shfl_down(s2, off);
    if (lane == 0) red[4 + wv] = s2;
    __syncthreads();
    const float var = (red[4] + red[5] + red[6] + red[7]) * (1.0f / 1024.0f);
    const float rs  = rsqrtf(var + 1e-5f);
    const float4 gv = *(const float4*)&g[tid * 4];
    const float4 bv = *(const float4*)&b[tid * 4];
    u16x4 o;
    o.x = f2bf(dx * rs * gv.x + bv.x);
    o.y = f2bf(dy * rs * gv.y + bv.y);
    o.z = f2bf(dz * rs * gv.z + bv.z);
    o.w = f2bf(dw * rs * gv.w + bv.w);
    *(u16x4*)&out[(size_t)row * 1024 + tid * 4] = o;
}

// ---------------- bf16 MFMA GEMM:  C[M,N] = A[M,K] @ Bt[N,K]^T (+epilogue)
// MODE 0: Ob = bf16(acc); 1: RES += acc+bias; 2: Ob = bf16(relu(acc+bias)); 3: Of = acc+bias
// 256x128 tile, BK=32, 4 waves of 128x64 (8x4 fragments). 1D grid, XCD swizzle.
// Double-buffered global_load_lds, one barrier per K-step.
template <int MODE>
__global__ __launch_bounds__(256, 2) void gemm_bt(const u16* __restrict__ A,
                                                  const u16* __restrict__ Bt,
                                                  const float* __restrict__ bias,
                                                  float* __restrict__ RES,
                                                  u16* __restrict__ Ob,
                                                  float* __restrict__ Of,
                                                  int N, int K, int ntx)
{
    __shared__ __align__(16) u16 As[2][256 * 32];
    __shared__ __align__(16) u16 Bs[2][128 * 32];
    const int tid  = threadIdx.x;
    const int lane = tid & 63, wave = tid >> 6;
    const int wr = wave >> 1, wc = wave & 1;
    const int l15 = lane & 15, l4 = lane >> 4;

    // XCD-bijective swizzle: contiguous chunk of blocks per XCD (nwg % 8 == 0)
    const int nwg = (int)gridDim.x;
    const int bid = (int)blockIdx.x;
    const int swz = (bid & 7) * (nwg >> 3) + (bid >> 3);
    const int n0 = (swz % ntx) * 128, m0 = (swz / ntx) * 256;

    f32x4 acc[8][4];
    const f32x4 zz = {0.f, 0.f, 0.f, 0.f};
#pragma unroll
    for (int i = 0; i < 8; ++i)
#pragma unroll
        for (int j = 0; j < 4; ++j) acc[i][j] = zz;

    // staging: A = 1024 chunks (4 rounds), B = 512 chunks (2 rounds); chunk -> row c>>2, quarter c&3
    const u16* Ag[4];
    const u16* Bg[2];
#pragma unroll
    for (int r = 0; r < 4; ++r) {
        const int c = r * 256 + tid;
        Ag[r] = &A[(size_t)(m0 + (c >> 2)) * K + (c & 3) * 8];
    }
#pragma unroll
    for (int r = 0; r < 2; ++r) {
        const int c = r * 256 + tid;
        Bg[r] = &Bt[(size_t)(n0 + (c >> 2)) * K + (c & 3) * 8];
    }

    // prologue: stage k0=0 into buf 0
#pragma unroll
    for (int r = 0; r < 4; ++r) gload16(Ag[r], &As[0][(r * 256 + tid) * 8]);
#pragma unroll
    for (int r = 0; r < 2; ++r) gload16(Bg[r], &Bs[0][(r * 256 + tid) * 8]);
    __syncthreads();

    const int S = K >> 5;
    int cur = 0;
    for (int s = 0; s < S; ++s) {
        if (s + 1 < S) {   // issue next-tile loads; they overlap this tile's MFMA
            const int kn = (s + 1) << 5;
#pragma unroll
            for (int r = 0; r < 4; ++r) gload16(Ag[r] + kn, &As[cur ^ 1][(r * 256 + tid) * 8]);
#pragma unroll
            for (int r = 0; r < 2; ++r) gload16(Bg[r] + kn, &Bs[cur ^ 1][(r * 256 + tid) * 8]);
        }
        s16x8 bw[4];
#pragma unroll
        for (int j = 0; j < 4; ++j)
            bw[j] = *(const s16x8*)&Bs[cur][(wc * 64 + j * 16 + l15) * 32 + l4 * 8];
#pragma unroll
        for (int i = 0; i < 8; ++i) {
            const s16x8 af = *(const s16x8*)&As[cur][(wr * 128 + i * 16 + l15) * 32 + l4 * 8];
#pragma unroll
            for (int j = 0; j < 4; ++j)
                acc[i][j] = __builtin_amdgcn_mfma_f32_16x16x32_bf16(
                    __builtin_bit_cast(bf16x8, af),
                    __builtin_bit_cast(bf16x8, bw[j]), acc[i][j], 0, 0, 0);
        }
        __syncthreads();   // drains next-tile loads (flew under MFMA) + syncs buffers
        cur ^= 1;
    }

    // epilogue; C/D layout: col = lane&15, row = (lane>>4)*4 + reg
#pragma unroll
    for (int i = 0; i < 8; ++i) {
        const int rb = m0 + wr * 128 + i * 16 + l4 * 4;
#pragma unroll
        for (int j = 0; j < 4; ++j) {
            const int col = n0 + wc * 64 + j * 16 + l15;
            const float bval = (MODE == 0) ? 0.0f : bias[col];
#pragma unroll
            for (int r = 0; r < 4; ++r) {
                const size_t o = (size_t)(rb + r) * N + col;
                const float v = acc[i][j][r];
                if (MODE == 0)      Ob[o] = f2bf(v);
                else if (MODE == 1) RES[o] += v + bval;
                else if (MODE == 2) Ob[o] = f2bf(fmaxf(v + bval, 0.0f));
                else                Of[o] = v + bval;
            }
        }
    }
}

// ---------------- MFMA flash attention (round-3 v2 + setprio), causal.
// grid (T/128, B*H) qt reversed; 4 waves; wave owns 32 q rows (2x16 frags).
// KV tiles of 64, single-buffered. QKV fused buffer (stride 3072).
__global__ __launch_bounds__(256) void attn_mfma_k(const u16* __restrict__ QKV,
                                                   u16* __restrict__ Og)
{
    const int qt  = (int)(gridDim.x - 1 - blockIdx.x);   // heavy blocks first
    const int bh  = blockIdx.y;
    const int b   = bh >> 4, h = bh & 15;
    const int tid = threadIdx.x;
    const int wq  = tid >> 6, lane = tid & 63;
    const int l15 = lane & 15, l4 = lane >> 4;

    __shared__ __align__(16) u16 Ks[64][72];     // K rows, 144B stride
    __shared__ __align__(16) u16 Vt[64][72];     // V^T rows d; u32 kv-pairs, rotated cols
    __shared__ __align__(16) u16 Ps[4][16][68];  // per-wave P (reused per qi)
    u32* VtW = (u32*)&Vt[0][0];                  // row stride 36 u32

    const int qrow0 = qt * 128 + wq * 32;

    const u16* Qbase = QKV + (size_t)b * 1024 * 3072 + h * 64;
    const u16* Kbase = Qbase + 1024;
    const u16* Vbase = Qbase + 2048;

    s16x8 aQ[2][2];
#pragma unroll
    for (int qi = 0; qi < 2; ++qi) {
        const u16* qsrc = Qbase + (size_t)(qrow0 + qi * 16 + l15) * 3072;
        aQ[qi][0] = *(const s16x8*)(qsrc + l4 * 8);
        aQ[qi][1] = *(const s16x8*)(qsrc + 32 + l4 * 8);
    }

    f32x4 O[2][4];
    const f32x4 zz = {0.f, 0.f, 0.f, 0.f};
    float mrow[2][4], lrow[2][4];
#pragma unroll
    for (int qi = 0; qi < 2; ++qi) {
#pragma unroll
        for (int dj = 0; dj < 4; ++dj) O[qi][dj] = zz;
#pragma unroll
        for (int r = 0; r < 4; ++r) { mrow[qi][r] = -3.0e38f; lrow[qi][r] = 0.f; }
    }

    const int srow = tid >> 3;              // K staging: rows 0..31 (+32)
    const int soff = (tid & 7) * 8;
    const int vp   = tid >> 3;              // V staging: kv-pair 0..31
    const int vdg  = tid & 7;               // d-group 0..7

    const int ntiles = 2 * qt + 2;
    for (int t = 0; t < ntiles; ++t) {
        const int kv0 = t * 64;
        __syncthreads();   // all waves done reading Ks/Vt of prev tile
        {
            const u16* kb0 = Kbase + (size_t)(kv0 + srow) * 3072 + soff;
            *(s16x8*)&Ks[srow][soff]      = *(const s16x8*)kb0;
            *(s16x8*)&Ks[srow + 32][soff] = *(const s16x8*)(kb0 + (size_t)32 * 3072);
        }
        {
            const u16* vb0 = Vbase + (size_t)(kv0 + 2 * vp) * 3072 + vdg * 8;
            s16x8 v0 = *(const s16x8*)vb0;
            s16x8 v1 = *(const s16x8*)(vb0 + 3072);
#pragma unroll
            for (int e = 0; e < 8; ++e) {
                const int d = vdg * 8 + e;
                const int c = (vp + 4 * vdg) & 31;   // rotated col
                u32 pk = (u32)(u16)v0[e] | ((u32)(u16)v1[e] << 16);
                VtW[d * 36 + c] = pk;
            }
        }
        __syncthreads();   // staging visible

#pragma unroll
        for (int qi = 0; qi < 2; ++qi) {
            const int qlo = qrow0 + qi * 16;
            if (kv0 > qlo + 15) continue;            // fully masked frag
            f32x4 S[4];
            __builtin_amdgcn_s_setprio(1);
#pragma unroll
            for (int kc = 0; kc < 4; ++kc) {
                f32x4 s = zz;
                s16x8 bK0 = *(const s16x8*)&Ks[kc * 16 + l15][l4 * 8];
                s16x8 bK1 = *(const s16x8*)&Ks[kc * 16 + l15][32 + l4 * 8];
                s = __builtin_amdgcn_mfma_f32_16x16x32_bf16(
                    __builtin_bit_cast(bf16x8, aQ[qi][0]), __builtin_bit_cast(bf16x8, bK0), s, 0, 0, 0);
                s = __builtin_amdgcn_mfma_f32_16x16x32_bf16(
                    __builtin_bit_cast(bf16x8, aQ[qi][1]), __builtin_bit_cast(bf16x8, bK1), s, 0, 0, 0);
#pragma unroll
                for (int r = 0; r < 4; ++r) S[kc][r] = s[r] * 0.125f;
            }
            __builtin_amdgcn_s_setprio(0);
            if (kv0 + 63 > qlo) {                     // diagonal: elementwise mask
#pragma unroll
                for (int kc = 0; kc < 4; ++kc) {
                    const int k = kv0 + kc * 16 + l15;
#pragma unroll
                    for (int r = 0; r < 4; ++r)
                        if (k > qlo + l4 * 4 + r) S[kc][r] = -3.0e38f;
                }
            }
            float mloc[4];
#pragma unroll
            for (int r = 0; r < 4; ++r)
                mloc[r] = fmaxf(fmaxf(S[0][r], S[1][r]), fmaxf(S[2][r], S[3][r]));
#pragma unroll
            for (int off = 1; off < 16; off <<= 1)
#pragma unroll
                for (int r = 0; r < 4; ++r) mloc[r] = fmaxf(mloc[r], __shfl_xor(mloc[r], off));
            float alpha[4];
#pragma unroll
            for (int r = 0; r < 4; ++r) {
                const float mnew = fmaxf(mrow[qi][r], mloc[r]);
                alpha[r] = __expf(mrow[qi][r] - mnew);
                mrow[qi][r] = mnew;
            }
            float psum[4] = {0.f, 0.f, 0.f, 0.f};
#pragma unroll
            for (int kc = 0; kc < 4; ++kc)
#pragma unroll
                for (int r = 0; r < 4; ++r) {
                    const float p = __expf(S[kc][r] - mrow[qi][r]);
                    Ps[wq][l4 * 4 + r][kc * 16 + l15] = f2bf(p);
                    psum[r] += p;
                }
#pragma unroll
            for (int off = 1; off < 16; off <<= 1)
#pragma unroll
                for (int r = 0; r < 4; ++r) psum[r] += __shfl_xor(psum[r], off);
#pragma unroll
            for (int r = 0; r < 4; ++r) lrow[qi][r] = lrow[qi][r] * alpha[r] + psum[r];
#pragma unroll
            for (int dj = 0; dj < 4; ++dj)
#pragma unroll
                for (int r = 0; r < 4; ++r) O[qi][dj][r] *= alpha[r];
            __builtin_amdgcn_s_setprio(1);
#pragma unroll
            for (int kk = 0; kk < 2; ++kk) {
                s16x8 aP = *(const s16x8*)&Ps[wq][l15][kk * 32 + l4 * 8];
#pragma unroll
                for (int dj = 0; dj < 4; ++dj) {
                    const int d = dj * 16 + l15;
                    const int c = (kk * 16 + l4 * 4 + 4 * ((d >> 3) & 7)) & 31;
                    s16x8 bV = *(const s16x8*)&VtW[d * 36 + c];
                    O[qi][dj] = __builtin_amdgcn_mfma_f32_16x16x32_bf16(
                        __builtin_bit_cast(bf16x8, aP), __builtin_bit_cast(bf16x8, bV),
                        O[qi][dj], 0, 0, 0);
                }
            }
            __builtin_amdgcn_s_setprio(0);
        }
    }
    // epilogue
#pragma unroll
    for (int qi = 0; qi < 2; ++qi)
#pragma unroll
        for (int dj = 0; dj < 4; ++dj)
#pragma unroll
            for (int r = 0; r < 4; ++r) {
                const size_t o = ((size_t)(b * 1024 + qrow0 + qi * 16 + l4 * 4 + r)) * 1024
                               + h * 64 + dj * 16 + l15;
                Og[o] = f2bf(O[qi][dj][r] / lrow[qi][r]);
            }
}

// ---------------- orchestration
extern "C" void kernel_launch(void* const* d_in, const int* in_sizes, int n_in,
                              void* d_out, int out_size, void* d_ws, size_t ws_size,
                              hipStream_t stream)
{
    (void)in_sizes; (void)n_in; (void)out_size; (void)ws_size;
    const int*   idx  = (const int*)  d_in[0];
    const float* tok  = (const float*)d_in[1];
    const float* pos  = (const float*)d_in[2];
    const float* Wq   = (const float*)d_in[3];
    const float* Wk   = (const float*)d_in[4];
    const float* Wv   = (const float*)d_in[5];
    const float* Wo   = (const float*)d_in[6];
    const float* bo   = (const float*)d_in[7];
    const float* ln1g = (const float*)d_in[8];
    const float* ln1b = (const float*)d_in[9];
    const float* ln2g = (const float*)d_in[10];
    const float* ln2b = (const float*)d_in[11];
    const float* W1   = (const float*)d_in[12];
    const float* b1   = (const float*)d_in[13];
    const float* W2   = (const float*)d_in[14];
    const float* b2   = (const float*)d_in[15];
    const float* lnfg = (const float*)d_in[16];
    const float* lnfb = (const float*)d_in[17];
    const float* Wh   = (const float*)d_in[18];
    const float* bh   = (const float*)d_in[19];

    char* p = (char*)d_ws;
    float* x  = (float*)p; p += (size_t)8192 * 1024 * 4;
    u16* h    = (u16*)p;   p += (size_t)8192 * 1024 * 2;
    u16* qkv  = (u16*)p;   p += (size_t)8192 * 3072 * 2;
    u16* ab   = (u16*)p;   p += (size_t)8192 * 1024 * 2;
    u16* fb   = (u16*)p;   p += (size_t)8192 * 4096 * 2;
    u16* wqT  = (u16*)p;   p += (size_t)1024 * 1024 * 2;   // wq/wk/wv contiguous -> [3072][1024]
    u16* wkT  = (u16*)p;   p += (size_t)1024 * 1024 * 2;
    u16* wvT  = (u16*)p;   p += (size_t)1024 * 1024 * 2;
    u16* woT  = (u16*)p;   p += (size_t)1024 * 1024 * 2;
    u16* w1T  = (u16*)p;   p += (size_t)1024 * 4096 * 2;
    u16* w2T  = (u16*)p;   p += (size_t)4096 * 1024 * 2;
    u16* whT  = (u16*)p;   p += (size_t)1024 * 256 * 2;

    const dim3 tb(32, 8);
    embed_k<<<8192, 256, 0, stream>>>(idx, tok, pos, x);
    for (int l = 0; l < 6; ++l) {
        transpose_k<<<dim3(32, 32),  tb, 0, stream>>>(Wq + (size_t)l * 1048576, wqT, 1024, 1024);
        transpose_k<<<dim3(32, 32),  tb, 0, stream>>>(Wk + (size_t)l * 1048576, wkT, 1024, 1024);
        transpose_k<<<dim3(32, 32),  tb, 0, stream>>>(Wv + (size_t)l * 1048576, wvT, 1024, 1024);
        transpose_k<<<dim3(32, 32),  tb, 0, stream>>>(Wo + (size_t)l * 1048576, woT, 1024, 1024);
        transpose_k<<<dim3(128, 32), tb, 0, stream>>>(W1 + (size_t)l * 4194304, w1T, 1024, 4096);
        transpose_k<<<dim3(32, 128), tb, 0, stream>>>(W2 + (size_t)l * 4194304, w2T, 4096, 1024);

        ln_k<<<8192, 256, 0, stream>>>(x, ln1g + l * 1024, ln1b + l * 1024, h);
        gemm_bt<0><<<768,  256, 0, stream>>>(h, wqT, nullptr, nullptr, qkv, nullptr, 3072, 1024, 24);
        attn_mfma_k<<<dim3(8, 128), 256, 0, stream>>>(qkv, ab);
        gemm_bt<1><<<256,  256, 0, stream>>>(ab, woT, bo + l * 1024, x, nullptr, nullptr, 1024, 1024, 8);
        ln_k<<<8192, 256, 0, stream>>>(x, ln2g + l * 1024, ln2b + l * 1024, h);
        gemm_bt<2><<<1024, 256, 0, stream>>>(h, w1T, b1 + l * 4096, nullptr, fb, nullptr, 4096, 1024, 32);
        gemm_bt<1><<<256,  256, 0, stream>>>(fb, w2T, b2 + l * 1024, x, nullptr, nullptr, 1024, 4096, 8);
    }
    transpose_k<<<dim3(8, 32), tb, 0, stream>>>(Wh, whT, 1024, 256);
    ln_k<<<8192, 256, 0, stream>>>(x, lnfg, lnfb, h);
    gemm_bt<3><<<64, 256, 0, stream>>>(h, whT, bh, nullptr, nullptr, (float*)d_out, 256, 1024, 2);
}

// Round 6
// 2706.481 us; speedup vs baseline: 1.1786x; 1.1786x over previous
//
#include <hip/hip_runtime.h>

typedef unsigned short u16;
typedef unsigned int   u32;
typedef __attribute__((ext_vector_type(4))) float  f32x4;
typedef __attribute__((ext_vector_type(8))) __bf16 bf16x8;
typedef __attribute__((ext_vector_type(8))) short  s16x8;
typedef __attribute__((ext_vector_type(4))) unsigned short u16x4;

#define DEVFN __device__ __forceinline__

DEVFN float bf2f(u16 u) {
    u32 v = ((u32)u) << 16;
    return __builtin_bit_cast(float, v);
}
DEVFN u16 f2bf(float f) {   // round-to-nearest-even
    u32 u = __builtin_bit_cast(u32, f);
    u32 r = u + 0x7FFFu + ((u >> 16) & 1u);
    return (u16)(r >> 16);
}

// async global->LDS, 16B per lane. LDS dest must be linear in lane order.
DEVFN void gload16(const void* g, void* l) {
    __builtin_amdgcn_global_load_lds(
        (const __attribute__((address_space(1))) void*)g,
        (__attribute__((address_space(3))) void*)l, 16, 0, 0);
}

// ---------------- embedding
__global__ __launch_bounds__(256) void embed_k(const int* __restrict__ idx,
                                               const float* __restrict__ tok,
                                               const float* __restrict__ pos,
                                               float* __restrict__ x)
{
    int i   = blockIdx.x * 256 + threadIdx.x;
    int row = i >> 8;
    int c   = (i & 255) << 2;
    int t   = row & 1023;
    int tk  = idx[row];
    float4 a = *(const float4*)&tok[(size_t)tk * 1024 + c];
    float4 p = *(const float4*)&pos[(size_t)t * 1024 + c];
    float4 r; r.x = a.x + p.x; r.y = a.y + p.y; r.z = a.z + p.z; r.w = a.w + p.w;
    *(float4*)&x[(size_t)row * 1024 + c] = r;
}

// ---------------- fp32 [K,N] -> bf16 [N,K] transpose (single matrix; head)
__global__ __launch_bounds__(256) void transpose_k(const float* __restrict__ W,
                                                   u16* __restrict__ Wt, int K, int N)
{
    __shared__ float tile[32][33];
    int n0 = blockIdx.x * 32, k0 = blockIdx.y * 32;
    int xx = threadIdx.x, ty = threadIdx.y;      // block (32,8)
#pragma unroll
    for (int yy = 0; yy < 4; ++yy) {
        int y = ty + yy * 8;
        tile[y][xx] = W[(size_t)(k0 + y) * N + n0 + xx];
    }
    __syncthreads();
#pragma unroll
    for (int yy = 0; yy < 4; ++yy) {
        int y = ty + yy * 8;
        Wt[(size_t)(n0 + y) * K + k0 + xx] = f2bf(tile[xx][y]);
    }
}

// ---------------- fused per-layer weight transpose: Wq/Wk/Wv/Wo/W1/W2 in ONE launch
// 12288 tiles of 32x32. ids: [0,3072) qkv, [3072,4096) wo, [4096,8192) W1, [8192,12288) W2
__global__ __launch_bounds__(256) void transpose_all_k(
    const float* __restrict__ Wq, const float* __restrict__ Wk,
    const float* __restrict__ Wv, const float* __restrict__ Wo,
    const float* __restrict__ W1, const float* __restrict__ W2,
    u16* __restrict__ qkvT, u16* __restrict__ woT,
    u16* __restrict__ w1T, u16* __restrict__ w2T)
{
    __shared__ float tile[32][33];
    const int id = blockIdx.x;
    const float* W; u16* Wt; int K, N, bx, by;
    if (id < 3072) {
        const int m = id >> 10, t2 = id & 1023;
        W = (m == 0) ? Wq : (m == 1) ? Wk : Wv;
        Wt = qkvT + (size_t)m * 1024 * 1024;
        K = 1024; N = 1024; bx = t2 & 31; by = t2 >> 5;
    } else if (id < 4096) {
        const int t2 = id - 3072;
        W = Wo; Wt = woT; K = 1024; N = 1024; bx = t2 & 31; by = t2 >> 5;
    } else if (id < 8192) {
        const int t2 = id - 4096;
        W = W1; Wt = w1T; K = 1024; N = 4096; bx = t2 & 127; by = t2 >> 7;
    } else {
        const int t2 = id - 8192;
        W = W2; Wt = w2T; K = 4096; N = 1024; bx = t2 & 31; by = t2 >> 5;
    }
    const int n0 = bx * 32, k0 = by * 32;
    const int xx = threadIdx.x, ty = threadIdx.y;    // block (32,8)
#pragma unroll
    for (int yy = 0; yy < 4; ++yy) {
        const int y = ty + yy * 8;
        tile[y][xx] = W[(size_t)(k0 + y) * N + n0 + xx];
    }
    __syncthreads();
#pragma unroll
    for (int yy = 0; yy < 4; ++yy) {
        const int y = ty + yy * 8;
        Wt[(size_t)(n0 + y) * K + k0 + xx] = f2bf(tile[xx][y]);
    }
}

// ---------------- LayerNorm: fp32 in -> bf16 out, C=1024, one block per row
__global__ __launch_bounds__(256) void ln_k(const float* __restrict__ x,
                                            const float* __restrict__ g,
                                            const float* __restrict__ b,
                                            u16* __restrict__ out)
{
    const int row = blockIdx.x, tid = threadIdx.x;
    const float4 v = *(const float4*)&x[(size_t)row * 1024 + tid * 4];
    __shared__ float red[8];
    float s = v.x + v.y + v.z + v.w;
#pragma unroll
    for (int off = 32; off > 0; off >>= 1) s += __shfl_down(s, off);
    const int lane = tid & 63, wv = tid >> 6;
    if (lane == 0) red[wv] = s;
    __syncthreads();
    const float mu = (red[0] + red[1] + red[2] + red[3]) * (1.0f / 1024.0f);
    const float dx = v.x - mu, dy = v.y - mu, dz = v.z - mu, dw = v.w - mu;
    float s2 = dx * dx + dy * dy + dz * dz + dw * dw;
#pragma unroll
    for (int off = 32; off > 0; off >>= 1) s2 += __shfl_down(s2, off);
    if (lane == 0) red[4 + wv] = s2;
    __syncthreads();
    const float var = (red[4] + red[5] + red[6] + red[7]) * (1.0f / 1024.0f);
    const float rs  = rsqrtf(var + 1e-5f);
    const float4 gv = *(const float4*)&g[tid * 4];
    const float4 bv = *(const float4*)&b[tid * 4];
    u16x4 o;
    o.x = f2bf(dx * rs * gv.x + bv.x);
    o.y = f2bf(dy * rs * gv.y + bv.y);
    o.z = f2bf(dz * rs * gv.z + bv.z);
    o.w = f2bf(dw * rs * gv.w + bv.w);
    *(u16x4*)&out[(size_t)row * 1024 + tid * 4] = o;
}

// ---------------- bf16 MFMA GEMM:  C[M,N] = A[M,K] @ Bt[N,K]^T (+epilogue)
// MODE 0: Ob = bf16(acc); 1: RES += acc+bias; 2: Ob = bf16(relu(acc+bias)); 3: Of = acc+bias
// 128x128 tile, BK=32, 4 waves. 1D grid (nwg%8==0), XCD-bijective swizzle.
// Double-buffered global_load_lds: one barrier per K-step, loads overlap MFMA.
// (256x128 regressed: occupancy 21->11%, MfmaUtil 21.6->16.8 — 2-barrier loops want 128².)
template <int MODE>
__global__ __launch_bounds__(256) void gemm_bt(const u16* __restrict__ A,
                                               const u16* __restrict__ Bt,
                                               const float* __restrict__ bias,
                                               float* __restrict__ RES,
                                               u16* __restrict__ Ob,
                                               float* __restrict__ Of,
                                               int N, int K, int ntx)
{
    __shared__ __align__(16) u16 As[2][128 * 32];
    __shared__ __align__(16) u16 Bs[2][128 * 32];
    const int tid  = threadIdx.x;
    const int lane = tid & 63, wave = tid >> 6;
    const int wr = wave >> 1, wc = wave & 1;
    const int l15 = lane & 15, l4 = lane >> 4;

    // XCD-bijective swizzle: contiguous chunk of blocks per XCD (nwg % 8 == 0)
    const int nwg = (int)gridDim.x;
    const int bid = (int)blockIdx.x;
    const int swz = (bid & 7) * (nwg >> 3) + (bid >> 3);
    const int n0 = (swz % ntx) * 128, m0 = (swz / ntx) * 128;

    f32x4 acc[4][4];
    const f32x4 zz = {0.f, 0.f, 0.f, 0.f};
#pragma unroll
    for (int i = 0; i < 4; ++i)
#pragma unroll
        for (int j = 0; j < 4; ++j) acc[i][j] = zz;

    const int r0 = tid >> 2, q0q = (tid & 3) * 8;
    const int r1 = (tid + 256) >> 2, q1q = ((tid + 256) & 3) * 8;
    const u16* Arow0 = &A [(size_t)(m0 + r0) * K + q0q];
    const u16* Brow0 = &Bt[(size_t)(n0 + r0) * K + q0q];
    const u16* Arow1 = &A [(size_t)(m0 + r1) * K + q1q];
    const u16* Brow1 = &Bt[(size_t)(n0 + r1) * K + q1q];

    // prologue: stage k0=0 into buf 0
    gload16(Arow0, &As[0][tid * 8]);
    gload16(Brow0, &Bs[0][tid * 8]);
    gload16(Arow1, &As[0][(tid + 256) * 8]);
    gload16(Brow1, &Bs[0][(tid + 256) * 8]);
    __syncthreads();

    const int S = K >> 5;
    int cur = 0;
    for (int s = 0; s < S; ++s) {
        if (s + 1 < S) {   // issue next-tile loads; they overlap this tile's MFMA
            const int kn = (s + 1) << 5;
            gload16(Arow0 + kn, &As[cur ^ 1][tid * 8]);
            gload16(Brow0 + kn, &Bs[cur ^ 1][tid * 8]);
            gload16(Arow1 + kn, &As[cur ^ 1][(tid + 256) * 8]);
            gload16(Brow1 + kn, &Bs[cur ^ 1][(tid + 256) * 8]);
        }
        s16x8 af[4], bw[4];
#pragma unroll
        for (int i = 0; i < 4; ++i)
            af[i] = *(const s16x8*)&As[cur][(wr * 64 + i * 16 + l15) * 32 + l4 * 8];
#pragma unroll
        for (int j = 0; j < 4; ++j)
            bw[j] = *(const s16x8*)&Bs[cur][(wc * 64 + j * 16 + l15) * 32 + l4 * 8];
#pragma unroll
        for (int i = 0; i < 4; ++i)
#pragma unroll
            for (int j = 0; j < 4; ++j)
                acc[i][j] = __builtin_amdgcn_mfma_f32_16x16x32_bf16(
                    __builtin_bit_cast(bf16x8, af[i]),
                    __builtin_bit_cast(bf16x8, bw[j]), acc[i][j], 0, 0, 0);
        __syncthreads();   // drains next-tile loads (flew under MFMA) + syncs buffers
        cur ^= 1;
    }

    // epilogue; C/D layout: col = lane&15, row = (lane>>4)*4 + reg
#pragma unroll
    for (int i = 0; i < 4; ++i) {
        const int rb = m0 + wr * 64 + i * 16 + l4 * 4;
#pragma unroll
        for (int j = 0; j < 4; ++j) {
            const int col = n0 + wc * 64 + j * 16 + l15;
            const float bval = (MODE == 0) ? 0.0f : bias[col];
#pragma unroll
            for (int r = 0; r < 4; ++r) {
                const size_t o = (size_t)(rb + r) * N + col;
                const float v = acc[i][j][r];
                if (MODE == 0)      Ob[o] = f2bf(v);
                else if (MODE == 1) RES[o] += v + bval;
                else if (MODE == 2) Ob[o] = f2bf(fmaxf(v + bval, 0.0f));
                else                Of[o] = v + bval;
            }
        }
    }
}

// ---------------- MFMA flash attention (v2 + setprio), causal.
// grid (T/128, B*H) qt reversed; 4 waves; wave owns 32 q rows (2x16 frags).
// KV tiles of 64, single-buffered. QKV fused buffer (stride 3072).
__global__ __launch_bounds__(256) void attn_mfma_k(const u16* __restrict__ QKV,
                                                   u16* __restrict__ Og)
{
    const int qt  = (int)(gridDim.x - 1 - blockIdx.x);   // heavy blocks first
    const int bh  = blockIdx.y;
    const int b   = bh >> 4, h = bh & 15;
    const int tid = threadIdx.x;
    const int wq  = tid >> 6, lane = tid & 63;
    const int l15 = lane & 15, l4 = lane >> 4;

    __shared__ __align__(16) u16 Ks[64][72];     // K rows, 144B stride
    __shared__ __align__(16) u16 Vt[64][72];     // V^T rows d; u32 kv-pairs, rotated cols
    __shared__ __align__(16) u16 Ps[4][16][68];  // per-wave P (reused per qi)
    u32* VtW = (u32*)&Vt[0][0];                  // row stride 36 u32

    const int qrow0 = qt * 128 + wq * 32;

    const u16* Qbase = QKV + (size_t)b * 1024 * 3072 + h * 64;
    const u16* Kbase = Qbase + 1024;
    const u16* Vbase = Qbase + 2048;

    s16x8 aQ[2][2];
#pragma unroll
    for (int qi = 0; qi < 2; ++qi) {
        const u16* qsrc = Qbase + (size_t)(qrow0 + qi * 16 + l15) * 3072;
        aQ[qi][0] = *(const s16x8*)(qsrc + l4 * 8);
        aQ[qi][1] = *(const s16x8*)(qsrc + 32 + l4 * 8);
    }

    f32x4 O[2][4];
    const f32x4 zz = {0.f, 0.f, 0.f, 0.f};
    float mrow[2][4], lrow[2][4];
#pragma unroll
    for (int qi = 0; qi < 2; ++qi) {
#pragma unroll
        for (int dj = 0; dj < 4; ++dj) O[qi][dj] = zz;
#pragma unroll
        for (int r = 0; r < 4; ++r) { mrow[qi][r] = -3.0e38f; lrow[qi][r] = 0.f; }
    }

    const int srow = tid >> 3;              // K staging: rows 0..31 (+32)
    const int soff = (tid & 7) * 8;
    const int vp   = tid >> 3;              // V staging: kv-pair 0..31
    const int vdg  = tid & 7;               // d-group 0..7

    const int ntiles = 2 * qt + 2;
    for (int t = 0; t < ntiles; ++t) {
        const int kv0 = t * 64;
        __syncthreads();   // all waves done reading Ks/Vt of prev tile
        {
            const u16* kb0 = Kbase + (size_t)(kv0 + srow) * 3072 + soff;
            *(s16x8*)&Ks[srow][soff]      = *(const s16x8*)kb0;
            *(s16x8*)&Ks[srow + 32][soff] = *(const s16x8*)(kb0 + (size_t)32 * 3072);
        }
        {
            const u16* vb0 = Vbase + (size_t)(kv0 + 2 * vp) * 3072 + vdg * 8;
            s16x8 v0 = *(const s16x8*)vb0;
            s16x8 v1 = *(const s16x8*)(vb0 + 3072);
#pragma unroll
            for (int e = 0; e < 8; ++e) {
                const int d = vdg * 8 + e;
                const int c = (vp + 4 * vdg) & 31;   // rotated col
                u32 pk = (u32)(u16)v0[e] | ((u32)(u16)v1[e] << 16);
                VtW[d * 36 + c] = pk;
            }
        }
        __syncthreads();   // staging visible

#pragma unroll
        for (int qi = 0; qi < 2; ++qi) {
            const int qlo = qrow0 + qi * 16;
            if (kv0 > qlo + 15) continue;            // fully masked frag
            f32x4 S[4];
            __builtin_amdgcn_s_setprio(1);
#pragma unroll
            for (int kc = 0; kc < 4; ++kc) {
                f32x4 s = zz;
                s16x8 bK0 = *(const s16x8*)&Ks[kc * 16 + l15][l4 * 8];
                s16x8 bK1 = *(const s16x8*)&Ks[kc * 16 + l15][32 + l4 * 8];
                s = __builtin_amdgcn_mfma_f32_16x16x32_bf16(
                    __builtin_bit_cast(bf16x8, aQ[qi][0]), __builtin_bit_cast(bf16x8, bK0), s, 0, 0, 0);
                s = __builtin_amdgcn_mfma_f32_16x16x32_bf16(
                    __builtin_bit_cast(bf16x8, aQ[qi][1]), __builtin_bit_cast(bf16x8, bK1), s, 0, 0, 0);
#pragma unroll
                for (int r = 0; r < 4; ++r) S[kc][r] = s[r] * 0.125f;
            }
            __builtin_amdgcn_s_setprio(0);
            if (kv0 + 63 > qlo) {                     // diagonal: elementwise mask
#pragma unroll
                for (int kc = 0; kc < 4; ++kc) {
                    const int k = kv0 + kc * 16 + l15;
#pragma unroll
                    for (int r = 0; r < 4; ++r)
                        if (k > qlo + l4 * 4 + r) S[kc][r] = -3.0e38f;
                }
            }
            float mloc[4];
#pragma unroll
            for (int r = 0; r < 4; ++r)
                mloc[r] = fmaxf(fmaxf(S[0][r], S[1][r]), fmaxf(S[2][r], S[3][r]));
#pragma unroll
            for (int off = 1; off < 16; off <<= 1)
#pragma unroll
                for (int r = 0; r < 4; ++r) mloc[r] = fmaxf(mloc[r], __shfl_xor(mloc[r], off));
            float alpha[4];
#pragma unroll
            for (int r = 0; r < 4; ++r) {
                const float mnew = fmaxf(mrow[qi][r], mloc[r]);
                alpha[r] = __expf(mrow[qi][r] - mnew);
                mrow[qi][r] = mnew;
            }
            float psum[4] = {0.f, 0.f, 0.f, 0.f};
#pragma unroll
            for (int kc = 0; kc < 4; ++kc)
#pragma unroll
                for (int r = 0; r < 4; ++r) {
                    const float p = __expf(S[kc][r] - mrow[qi][r]);
                    Ps[wq][l4 * 4 + r][kc * 16 + l15] = f2bf(p);
                    psum[r] += p;
                }
#pragma unroll
            for (int off = 1; off < 16; off <<= 1)
#pragma unroll
                for (int r = 0; r < 4; ++r) psum[r] += __shfl_xor(psum[r], off);
#pragma unroll
            for (int r = 0; r < 4; ++r) lrow[qi][r] = lrow[qi][r] * alpha[r] + psum[r];
#pragma unroll
            for (int dj = 0; dj < 4; ++dj)
#pragma unroll
                for (int r = 0; r < 4; ++r) O[qi][dj][r] *= alpha[r];
            __builtin_amdgcn_s_setprio(1);
#pragma unroll
            for (int kk = 0; kk < 2; ++kk) {
                s16x8 aP = *(const s16x8*)&Ps[wq][l15][kk * 32 + l4 * 8];
#pragma unroll
                for (int dj = 0; dj < 4; ++dj) {
                    const int d = dj * 16 + l15;
                    const int c = (kk * 16 + l4 * 4 + 4 * ((d >> 3) & 7)) & 31;
                    s16x8 bV = *(const s16x8*)&VtW[d * 36 + c];
                    O[qi][dj] = __builtin_amdgcn_mfma_f32_16x16x32_bf16(
                        __builtin_bit_cast(bf16x8, aP), __builtin_bit_cast(bf16x8, bV),
                        O[qi][dj], 0, 0, 0);
                }
            }
            __builtin_amdgcn_s_setprio(0);
        }
    }
    // epilogue
#pragma unroll
    for (int qi = 0; qi < 2; ++qi)
#pragma unroll
        for (int dj = 0; dj < 4; ++dj)
#pragma unroll
            for (int r = 0; r < 4; ++r) {
                const size_t o = ((size_t)(b * 1024 + qrow0 + qi * 16 + l4 * 4 + r)) * 1024
                               + h * 64 + dj * 16 + l15;
                Og[o] = f2bf(O[qi][dj][r] / lrow[qi][r]);
            }
}

// ---------------- orchestration
extern "C" void kernel_launch(void* const* d_in, const int* in_sizes, int n_in,
                              void* d_out, int out_size, void* d_ws, size_t ws_size,
                              hipStream_t stream)
{
    (void)in_sizes; (void)n_in; (void)out_size; (void)ws_size;
    const int*   idx  = (const int*)  d_in[0];
    const float* tok  = (const float*)d_in[1];
    const float* pos  = (const float*)d_in[2];
    const float* Wq   = (const float*)d_in[3];
    const float* Wk   = (const float*)d_in[4];
    const float* Wv   = (const float*)d_in[5];
    const float* Wo   = (const float*)d_in[6];
    const float* bo   = (const float*)d_in[7];
    const float* ln1g = (const float*)d_in[8];
    const float* ln1b = (const float*)d_in[9];
    const float* ln2g = (const float*)d_in[10];
    const float* ln2b = (const float*)d_in[11];
    const float* W1   = (const float*)d_in[12];
    const float* b1   = (const float*)d_in[13];
    const float* W2   = (const float*)d_in[14];
    const float* b2   = (const float*)d_in[15];
    const float* lnfg = (const float*)d_in[16];
    const float* lnfb = (const float*)d_in[17];
    const float* Wh   = (const float*)d_in[18];
    const float* bh   = (const float*)d_in[19];

    char* p = (char*)d_ws;
    float* x  = (float*)p; p += (size_t)8192 * 1024 * 4;
    u16* h    = (u16*)p;   p += (size_t)8192 * 1024 * 2;
    u16* qkv  = (u16*)p;   p += (size_t)8192 * 3072 * 2;
    u16* ab   = (u16*)p;   p += (size_t)8192 * 1024 * 2;
    u16* fb   = (u16*)p;   p += (size_t)8192 * 4096 * 2;
    u16* wqT  = (u16*)p;   p += (size_t)1024 * 1024 * 2;   // wq/wk/wv contiguous -> [3072][1024]
    u16* wkT  = (u16*)p;   p += (size_t)1024 * 1024 * 2;
    u16* wvT  = (u16*)p;   p += (size_t)1024 * 1024 * 2;
    u16* woT  = (u16*)p;   p += (size_t)1024 * 1024 * 2;
    u16* w1T  = (u16*)p;   p += (size_t)1024 * 4096 * 2;
    u16* w2T  = (u16*)p;   p += (size_t)4096 * 1024 * 2;
    u16* whT  = (u16*)p;   p += (size_t)1024 * 256 * 2;
    (void)wkT; (void)wvT;

    const dim3 tb(32, 8);
    embed_k<<<8192, 256, 0, stream>>>(idx, tok, pos, x);
    for (int l = 0; l < 6; ++l) {
        transpose_all_k<<<12288, tb, 0, stream>>>(
            Wq + (size_t)l * 1048576, Wk + (size_t)l * 1048576,
            Wv + (size_t)l * 1048576, Wo + (size_t)l * 1048576,
            W1 + (size_t)l * 4194304, W2 + (size_t)l * 4194304,
            wqT, woT, w1T, w2T);

        ln_k<<<8192, 256, 0, stream>>>(x, ln1g + l * 1024, ln1b + l * 1024, h);
        gemm_bt<0><<<1536, 256, 0, stream>>>(h, wqT, nullptr, nullptr, qkv, nullptr, 3072, 1024, 24);
        attn_mfma_k<<<dim3(8, 128), 256, 0, stream>>>(qkv, ab);
        gemm_bt<1><<<512,  256, 0, stream>>>(ab, woT, bo + l * 1024, x, nullptr, nullptr, 1024, 1024, 8);
        ln_k<<<8192, 256, 0, stream>>>(x, ln2g + l * 1024, ln2b + l * 1024, h);
        gemm_bt<2><<<2048, 256, 0, stream>>>(h, w1T, b1 + l * 4096, nullptr, fb, nullptr, 4096, 1024, 32);
        gemm_bt<1><<<512,  256, 0, stream>>>(fb, w2T, b2 + l * 1024, x, nullptr, nullptr, 1024, 4096, 8);
    }
    transpose_k<<<dim3(8, 32), tb, 0, stream>>>(Wh, whT, 1024, 256);
    ln_k<<<8192, 256, 0, stream>>>(x, lnfg, lnfb, h);
    gemm_bt<3><<<128, 256, 0, stream>>>(h, whT, bh, nullptr, nullptr, (float*)d_out, 256, 1024, 2);
}

// Round 7
// 2642.437 us; speedup vs baseline: 1.2072x; 1.0242x over previous
//
#include <hip/hip_runtime.h>

typedef unsigned short u16;
typedef unsigned int   u32;
typedef __attribute__((ext_vector_type(4))) float  f32x4;
typedef __attribute__((ext_vector_type(8))) __bf16 bf16x8;
typedef __attribute__((ext_vector_type(8))) short  s16x8;
typedef __attribute__((ext_vector_type(4))) unsigned short u16x4;

#define DEVFN __device__ __forceinline__

DEVFN float bf2f(u16 u) {
    u32 v = ((u32)u) << 16;
    return __builtin_bit_cast(float, v);
}
DEVFN u16 f2bf(float f) {   // round-to-nearest-even
    u32 u = __builtin_bit_cast(u32, f);
    u32 r = u + 0x7FFFu + ((u >> 16) & 1u);
    return (u16)(r >> 16);
}

// async global->LDS, 16B per lane. LDS dest must be linear in lane order.
DEVFN void gload16(const void* g, void* l) {
    __builtin_amdgcn_global_load_lds(
        (const __attribute__((address_space(1))) void*)g,
        (__attribute__((address_space(3))) void*)l, 16, 0, 0);
}

// ---------------- embedding
__global__ __launch_bounds__(256) void embed_k(const int* __restrict__ idx,
                                               const float* __restrict__ tok,
                                               const float* __restrict__ pos,
                                               float* __restrict__ x)
{
    int i   = blockIdx.x * 256 + threadIdx.x;
    int row = i >> 8;
    int c   = (i & 255) << 2;
    int t   = row & 1023;
    int tk  = idx[row];
    float4 a = *(const float4*)&tok[(size_t)tk * 1024 + c];
    float4 p = *(const float4*)&pos[(size_t)t * 1024 + c];
    float4 r; r.x = a.x + p.x; r.y = a.y + p.y; r.z = a.z + p.z; r.w = a.w + p.w;
    *(float4*)&x[(size_t)row * 1024 + c] = r;
}

// ---------------- fp32 [K,N] -> bf16 [N,K] transpose (single matrix; head)
__global__ __launch_bounds__(256) void transpose_k(const float* __restrict__ W,
                                                   u16* __restrict__ Wt, int K, int N)
{
    __shared__ float tile[32][33];
    int n0 = blockIdx.x * 32, k0 = blockIdx.y * 32;
    int xx = threadIdx.x, ty = threadIdx.y;      // block (32,8)
#pragma unroll
    for (int yy = 0; yy < 4; ++yy) {
        int y = ty + yy * 8;
        tile[y][xx] = W[(size_t)(k0 + y) * N + n0 + xx];
    }
    __syncthreads();
#pragma unroll
    for (int yy = 0; yy < 4; ++yy) {
        int y = ty + yy * 8;
        Wt[(size_t)(n0 + y) * K + k0 + xx] = f2bf(tile[xx][y]);
    }
}

// ---------------- fused per-layer weight transpose: Wq/Wk/Wv/Wo/W1/W2 in ONE launch
__global__ __launch_bounds__(256) void transpose_all_k(
    const float* __restrict__ Wq, const float* __restrict__ Wk,
    const float* __restrict__ Wv, const float* __restrict__ Wo,
    const float* __restrict__ W1, const float* __restrict__ W2,
    u16* __restrict__ qkvT, u16* __restrict__ woT,
    u16* __restrict__ w1T, u16* __restrict__ w2T)
{
    __shared__ float tile[32][33];
    const int id = blockIdx.x;
    const float* W; u16* Wt; int K, N, bx, by;
    if (id < 3072) {
        const int m = id >> 10, t2 = id & 1023;
        W = (m == 0) ? Wq : (m == 1) ? Wk : Wv;
        Wt = qkvT + (size_t)m * 1024 * 1024;
        K = 1024; N = 1024; bx = t2 & 31; by = t2 >> 5;
    } else if (id < 4096) {
        const int t2 = id - 3072;
        W = Wo; Wt = woT; K = 1024; N = 1024; bx = t2 & 31; by = t2 >> 5;
    } else if (id < 8192) {
        const int t2 = id - 4096;
        W = W1; Wt = w1T; K = 1024; N = 4096; bx = t2 & 127; by = t2 >> 7;
    } else {
        const int t2 = id - 8192;
        W = W2; Wt = w2T; K = 4096; N = 1024; bx = t2 & 31; by = t2 >> 5;
    }
    const int n0 = bx * 32, k0 = by * 32;
    const int xx = threadIdx.x, ty = threadIdx.y;    // block (32,8)
#pragma unroll
    for (int yy = 0; yy < 4; ++yy) {
        const int y = ty + yy * 8;
        tile[y][xx] = W[(size_t)(k0 + y) * N + n0 + xx];
    }
    __syncthreads();
#pragma unroll
    for (int yy = 0; yy < 4; ++yy) {
        const int y = ty + yy * 8;
        Wt[(size_t)(n0 + y) * K + k0 + xx] = f2bf(tile[xx][y]);
    }
}

// ---------------- LayerNorm: fp32 in -> bf16 out, C=1024, one block per row
__global__ __launch_bounds__(256) void ln_k(const float* __restrict__ x,
                                            const float* __restrict__ g,
                                            const float* __restrict__ b,
                                            u16* __restrict__ out)
{
    const int row = blockIdx.x, tid = threadIdx.x;
    const float4 v = *(const float4*)&x[(size_t)row * 1024 + tid * 4];
    __shared__ float red[8];
    float s = v.x + v.y + v.z + v.w;
#pragma unroll
    for (int off = 32; off > 0; off >>= 1) s += __shfl_down(s, off);
    const int lane = tid & 63, wv = tid >> 6;
    if (lane == 0) red[wv] = s;
    __syncthreads();
    const float mu = (red[0] + red[1] + red[2] + red[3]) * (1.0f / 1024.0f);
    const float dx = v.x - mu, dy = v.y - mu, dz = v.z - mu, dw = v.w - mu;
    float s2 = dx * dx + dy * dy + dz * dz + dw * dw;
#pragma unroll
    for (int off = 32; off > 0; off >>= 1) s2 += __shfl_down(s2, off);
    if (lane == 0) red[4 + wv] = s2;
    __syncthreads();
    const float var = (red[4] + red[5] + red[6] + red[7]) * (1.0f / 1024.0f);
    const float rs  = rsqrtf(var + 1e-5f);
    const float4 gv = *(const float4*)&g[tid * 4];
    const float4 bv = *(const float4*)&b[tid * 4];
    u16x4 o;
    o.x = f2bf(dx * rs * gv.x + bv.x);
    o.y = f2bf(dy * rs * gv.y + bv.y);
    o.z = f2bf(dz * rs * gv.z + bv.z);
    o.w = f2bf(dw * rs * gv.w + bv.w);
    *(u16x4*)&out[(size_t)row * 1024 + tid * 4] = o;
}

// ---------------- bf16 MFMA GEMM (unchanged, proven):  C = A @ Bt^T (+epilogue)
// 128x128 tile, BK=32, 4 waves, XCD-bijective swizzle, dbuf global_load_lds.
template <int MODE>
__global__ __launch_bounds__(256) void gemm_bt(const u16* __restrict__ A,
                                               const u16* __restrict__ Bt,
                                               const float* __restrict__ bias,
                                               float* __restrict__ RES,
                                               u16* __restrict__ Ob,
                                               float* __restrict__ Of,
                                               int N, int K, int ntx)
{
    __shared__ __align__(16) u16 As[2][128 * 32];
    __shared__ __align__(16) u16 Bs[2][128 * 32];
    const int tid  = threadIdx.x;
    const int lane = tid & 63, wave = tid >> 6;
    const int wr = wave >> 1, wc = wave & 1;
    const int l15 = lane & 15, l4 = lane >> 4;

    const int nwg = (int)gridDim.x;
    const int bid = (int)blockIdx.x;
    const int swz = (bid & 7) * (nwg >> 3) + (bid >> 3);
    const int n0 = (swz % ntx) * 128, m0 = (swz / ntx) * 128;

    f32x4 acc[4][4];
    const f32x4 zz = {0.f, 0.f, 0.f, 0.f};
#pragma unroll
    for (int i = 0; i < 4; ++i)
#pragma unroll
        for (int j = 0; j < 4; ++j) acc[i][j] = zz;

    const int r0 = tid >> 2, q0q = (tid & 3) * 8;
    const int r1 = (tid + 256) >> 2, q1q = ((tid + 256) & 3) * 8;
    const u16* Arow0 = &A [(size_t)(m0 + r0) * K + q0q];
    const u16* Brow0 = &Bt[(size_t)(n0 + r0) * K + q0q];
    const u16* Arow1 = &A [(size_t)(m0 + r1) * K + q1q];
    const u16* Brow1 = &Bt[(size_t)(n0 + r1) * K + q1q];

    gload16(Arow0, &As[0][tid * 8]);
    gload16(Brow0, &Bs[0][tid * 8]);
    gload16(Arow1, &As[0][(tid + 256) * 8]);
    gload16(Brow1, &Bs[0][(tid + 256) * 8]);
    __syncthreads();

    const int S = K >> 5;
    int cur = 0;
    for (int s = 0; s < S; ++s) {
        if (s + 1 < S) {
            const int kn = (s + 1) << 5;
            gload16(Arow0 + kn, &As[cur ^ 1][tid * 8]);
            gload16(Brow0 + kn, &Bs[cur ^ 1][tid * 8]);
            gload16(Arow1 + kn, &As[cur ^ 1][(tid + 256) * 8]);
            gload16(Brow1 + kn, &Bs[cur ^ 1][(tid + 256) * 8]);
        }
        s16x8 af[4], bw[4];
#pragma unroll
        for (int i = 0; i < 4; ++i)
            af[i] = *(const s16x8*)&As[cur][(wr * 64 + i * 16 + l15) * 32 + l4 * 8];
#pragma unroll
        for (int j = 0; j < 4; ++j)
            bw[j] = *(const s16x8*)&Bs[cur][(wc * 64 + j * 16 + l15) * 32 + l4 * 8];
#pragma unroll
        for (int i = 0; i < 4; ++i)
#pragma unroll
            for (int j = 0; j < 4; ++j)
                acc[i][j] = __builtin_amdgcn_mfma_f32_16x16x32_bf16(
                    __builtin_bit_cast(bf16x8, af[i]),
                    __builtin_bit_cast(bf16x8, bw[j]), acc[i][j], 0, 0, 0);
        __syncthreads();
        cur ^= 1;
    }

#pragma unroll
    for (int i = 0; i < 4; ++i) {
        const int rb = m0 + wr * 64 + i * 16 + l4 * 4;
#pragma unroll
        for (int j = 0; j < 4; ++j) {
            const int col = n0 + wc * 64 + j * 16 + l15;
            const float bval = (MODE == 0) ? 0.0f : bias[col];
#pragma unroll
            for (int r = 0; r < 4; ++r) {
                const size_t o = (size_t)(rb + r) * N + col;
                const float v = acc[i][j][r];
                if (MODE == 0)      Ob[o] = f2bf(v);
                else if (MODE == 1) RES[o] += v + bval;
                else if (MODE == 2) Ob[o] = f2bf(fmaxf(v + bval, 0.0f));
                else                Of[o] = v + bval;
            }
        }
    }
}

// ---------------- MFMA flash attention v4, causal.
// v2 + setprio + (K via global_load_lds w/ row-XOR swizzle) + deferred-l + defer-max.
// grid (T/128, B*H) qt reversed; 4 waves; wave owns 32 q rows (2x16 frags).
__global__ __launch_bounds__(256) void attn_mfma_k(const u16* __restrict__ QKV,
                                                   u16* __restrict__ Og)
{
    const int qt  = (int)(gridDim.x - 1 - blockIdx.x);   // heavy blocks first
    const int bh  = blockIdx.y;
    const int b   = bh >> 4, h = bh & 15;
    const int tid = threadIdx.x;
    const int wq  = tid >> 6, lane = tid & 63;
    const int l15 = lane & 15, l4 = lane >> 4;

    __shared__ __align__(16) u16 Ks[64 * 64];    // K rows, LINEAR + chunk XOR swizzle
    __shared__ __align__(16) u16 Vt[64][72];     // V^T rows d; u32 kv-pairs, rotated cols
    __shared__ __align__(16) u16 Ps[4][16][68];  // per-wave P
    u32* VtW = (u32*)&Vt[0][0];                  // row stride 36 u32

    const int qrow0 = qt * 128 + wq * 32;

    const u16* Qbase = QKV + (size_t)b * 1024 * 3072 + h * 64;
    const u16* Kbase = Qbase + 1024;
    const u16* Vbase = Qbase + 2048;

    s16x8 aQ[2][2];
#pragma unroll
    for (int qi = 0; qi < 2; ++qi) {
        const u16* qsrc = Qbase + (size_t)(qrow0 + qi * 16 + l15) * 3072;
        aQ[qi][0] = *(const s16x8*)(qsrc + l4 * 8);
        aQ[qi][1] = *(const s16x8*)(qsrc + 32 + l4 * 8);
    }

    f32x4 O[2][4];
    const f32x4 zz = {0.f, 0.f, 0.f, 0.f};
    float mrow[2][4], lrow[2][4];
#pragma unroll
    for (int qi = 0; qi < 2; ++qi) {
#pragma unroll
        for (int dj = 0; dj < 4; ++dj) O[qi][dj] = zz;
#pragma unroll
        for (int r = 0; r < 4; ++r) { mrow[qi][r] = -3.0e38f; lrow[qi][r] = 0.f; }
    }

    // K staging via gload_lds: physical chunk cw holds logical chunk cw^((cw>>3)&7)
    const int cw0 = tid, cw1 = 256 + tid;
    const int kr0 = cw0 >> 3, kc0 = ((cw0 & 7) ^ (kr0 & 7)) * 8;
    const int kr1 = cw1 >> 3, kc1 = ((cw1 & 7) ^ (kr1 & 7)) * 8;
    // V staging (reg->LDS transpose, rotated cols)
    const int vp  = tid >> 3;               // kv-pair 0..31
    const int vdg = tid & 7;                // d-group 0..7
    const int vc  = (vp + 4 * vdg) & 31;    // rotated col

    const int ntiles = 2 * qt + 2;
    for (int t = 0; t < ntiles; ++t) {
        const int kv0 = t * 64;
        __syncthreads();   // all waves done reading Ks/Vt of prev tile
        gload16(Kbase + (size_t)(kv0 + kr0) * 3072 + kc0, &Ks[cw0 * 8]);
        gload16(Kbase + (size_t)(kv0 + kr1) * 3072 + kc1, &Ks[cw1 * 8]);
        {
            const u16* vb0 = Vbase + (size_t)(kv0 + 2 * vp) * 3072 + vdg * 8;
            s16x8 v0 = *(const s16x8*)vb0;
            s16x8 v1 = *(const s16x8*)(vb0 + 3072);
#pragma unroll
            for (int e = 0; e < 8; ++e) {
                u32 pk = (u32)(u16)v0[e] | ((u32)(u16)v1[e] << 16);
                VtW[(vdg * 8 + e) * 36 + vc] = pk;
            }
        }
        __syncthreads();   // drains vmcnt+lgkmcnt -> staging visible

#pragma unroll
        for (int qi = 0; qi < 2; ++qi) {
            const int qlo = qrow0 + qi * 16;
            if (kv0 > qlo + 15) continue;            // fully masked frag
            f32x4 S[4];
            __builtin_amdgcn_s_setprio(1);
#pragma unroll
            for (int kc = 0; kc < 4; ++kc) {
                const int row = kc * 16 + l15;
                const int sw = (row & 7) << 4;
                const char* Kb = (const char*)Ks;
                f32x4 s = zz;
                s16x8 bK0 = *(const s16x8*)(Kb + ((row * 128 + l4 * 16) ^ sw));
                s16x8 bK1 = *(const s16x8*)(Kb + ((row * 128 + 64 + l4 * 16) ^ sw));
                s = __builtin_amdgcn_mfma_f32_16x16x32_bf16(
                    __builtin_bit_cast(bf16x8, aQ[qi][0]), __builtin_bit_cast(bf16x8, bK0), s, 0, 0, 0);
                s = __builtin_amdgcn_mfma_f32_16x16x32_bf16(
                    __builtin_bit_cast(bf16x8, aQ[qi][1]), __builtin_bit_cast(bf16x8, bK1), s, 0, 0, 0);
#pragma unroll
                for (int r = 0; r < 4; ++r) S[kc][r] = s[r] * 0.125f;
            }
            __builtin_amdgcn_s_setprio(0);
            if (kv0 + 63 > qlo) {                     // diagonal: elementwise mask
#pragma unroll
                for (int kc = 0; kc < 4; ++kc) {
                    const int k = kv0 + kc * 16 + l15;
#pragma unroll
                    for (int r = 0; r < 4; ++r)
                        if (k > qlo + l4 * 4 + r) S[kc][r] = -3.0e38f;
                }
            }
            float mloc[4];
#pragma unroll
            for (int r = 0; r < 4; ++r)
                mloc[r] = fmaxf(fmaxf(S[0][r], S[1][r]), fmaxf(S[2][r], S[3][r]));
#pragma unroll
            for (int off = 1; off < 16; off <<= 1)
#pragma unroll
                for (int r = 0; r < 4; ++r) mloc[r] = fmaxf(mloc[r], __shfl_xor(mloc[r], off));
            // defer-max (T13): skip rescale when max growth <= 8 for all rows (wave vote)
            bool stable = (mloc[0] <= mrow[qi][0] + 8.f) && (mloc[1] <= mrow[qi][1] + 8.f)
                       && (mloc[2] <= mrow[qi][2] + 8.f) && (mloc[3] <= mrow[qi][3] + 8.f);
            if (!__all(stable)) {
#pragma unroll
                for (int r = 0; r < 4; ++r) {
                    const float mnew = fmaxf(mrow[qi][r], mloc[r]);
                    const float al = __expf(mrow[qi][r] - mnew);
                    mrow[qi][r] = mnew;
                    lrow[qi][r] *= al;
#pragma unroll
                    for (int dj = 0; dj < 4; ++dj) O[qi][dj][r] *= al;
                }
            }
            // p + per-lane partial l (reduction deferred to epilogue)
#pragma unroll
            for (int kc = 0; kc < 4; ++kc)
#pragma unroll
                for (int r = 0; r < 4; ++r) {
                    const float p = __expf(S[kc][r] - mrow[qi][r]);
                    Ps[wq][l4 * 4 + r][kc * 16 + l15] = f2bf(p);
                    lrow[qi][r] += p;
                }
            __builtin_amdgcn_s_setprio(1);
#pragma unroll
            for (int kk = 0; kk < 2; ++kk) {
                s16x8 aP = *(const s16x8*)&Ps[wq][l15][kk * 32 + l4 * 8];
#pragma unroll
                for (int dj = 0; dj < 4; ++dj) {
                    const int d = dj * 16 + l15;
                    const int c = (kk * 16 + l4 * 4 + 4 * ((d >> 3) & 7)) & 31;
                    s16x8 bV = *(const s16x8*)&VtW[d * 36 + c];
                    O[qi][dj] = __builtin_amdgcn_mfma_f32_16x16x32_bf16(
                        __builtin_bit_cast(bf16x8, aP), __builtin_bit_cast(bf16x8, bV),
                        O[qi][dj], 0, 0, 0);
                }
            }
            __builtin_amdgcn_s_setprio(0);
        }
    }
    // epilogue: reduce per-lane partial l over the 16-lane col group, then O/l
#pragma unroll
    for (int qi = 0; qi < 2; ++qi)
#pragma unroll
        for (int r = 0; r < 4; ++r) {
            float s = lrow[qi][r];
#pragma unroll
            for (int off = 1; off < 16; off <<= 1) s += __shfl_xor(s, off);
            lrow[qi][r] = s;
        }
#pragma unroll
    for (int qi = 0; qi < 2; ++qi)
#pragma unroll
        for (int dj = 0; dj < 4; ++dj)
#pragma unroll
            for (int r = 0; r < 4; ++r) {
                const size_t o = ((size_t)(b * 1024 + qrow0 + qi * 16 + l4 * 4 + r)) * 1024
                               + h * 64 + dj * 16 + l15;
                Og[o] = f2bf(O[qi][dj][r] / lrow[qi][r]);
            }
}

// ---------------- orchestration
extern "C" void kernel_launch(void* const* d_in, const int* in_sizes, int n_in,
                              void* d_out, int out_size, void* d_ws, size_t ws_size,
                              hipStream_t stream)
{
    (void)in_sizes; (void)n_in; (void)out_size; (void)ws_size;
    const int*   idx  = (const int*)  d_in[0];
    const float* tok  = (const float*)d_in[1];
    const float* pos  = (const float*)d_in[2];
    const float* Wq   = (const float*)d_in[3];
    const float* Wk   = (const float*)d_in[4];
    const float* Wv   = (const float*)d_in[5];
    const float* Wo   = (const float*)d_in[6];
    const float* bo   = (const float*)d_in[7];
    const float* ln1g = (const float*)d_in[8];
    const float* ln1b = (const float*)d_in[9];
    const float* ln2g = (const float*)d_in[10];
    const float* ln2b = (const float*)d_in[11];
    const float* W1   = (const float*)d_in[12];
    const float* b1   = (const float*)d_in[13];
    const float* W2   = (const float*)d_in[14];
    const float* b2   = (const float*)d_in[15];
    const float* lnfg = (const float*)d_in[16];
    const float* lnfb = (const float*)d_in[17];
    const float* Wh   = (const float*)d_in[18];
    const float* bh   = (const float*)d_in[19];

    char* p = (char*)d_ws;
    float* x  = (float*)p; p += (size_t)8192 * 1024 * 4;
    u16* h    = (u16*)p;   p += (size_t)8192 * 1024 * 2;
    u16* qkv  = (u16*)p;   p += (size_t)8192 * 3072 * 2;
    u16* ab   = (u16*)p;   p += (size_t)8192 * 1024 * 2;
    u16* fb   = (u16*)p;   p += (size_t)8192 * 4096 * 2;
    u16* wqT  = (u16*)p;   p += (size_t)1024 * 1024 * 2;   // wq/wk/wv contiguous -> [3072][1024]
    u16* wkT  = (u16*)p;   p += (size_t)1024 * 1024 * 2;
    u16* wvT  = (u16*)p;   p += (size_t)1024 * 1024 * 2;
    u16* woT  = (u16*)p;   p += (size_t)1024 * 1024 * 2;
    u16* w1T  = (u16*)p;   p += (size_t)1024 * 4096 * 2;
    u16* w2T  = (u16*)p;   p += (size_t)4096 * 1024 * 2;
    u16* whT  = (u16*)p;   p += (size_t)1024 * 256 * 2;
    (void)wkT; (void)wvT;

    const dim3 tb(32, 8);
    embed_k<<<8192, 256, 0, stream>>>(idx, tok, pos, x);
    for (int l = 0; l < 6; ++l) {
        transpose_all_k<<<12288, tb, 0, stream>>>(
            Wq + (size_t)l * 1048576, Wk + (size_t)l * 1048576,
            Wv + (size_t)l * 1048576, Wo + (size_t)l * 1048576,
            W1 + (size_t)l * 4194304, W2 + (size_t)l * 4194304,
            wqT, woT, w1T, w2T);

        ln_k<<<8192, 256, 0, stream>>>(x, ln1g + l * 1024, ln1b + l * 1024, h);
        gemm_bt<0><<<1536, 256, 0, stream>>>(h, wqT, nullptr, nullptr, qkv, nullptr, 3072, 1024, 24);
        attn_mfma_k<<<dim3(8, 128), 256, 0, stream>>>(qkv, ab);
        gemm_bt<1><<<512,  256, 0, stream>>>(ab, woT, bo + l * 1024, x, nullptr, nullptr, 1024, 1024, 8);
        ln_k<<<8192, 256, 0, stream>>>(x, ln2g + l * 1024, ln2b + l * 1024, h);
        gemm_bt<2><<<2048, 256, 0, stream>>>(h, w1T, b1 + l * 4096, nullptr, fb, nullptr, 4096, 1024, 32);
        gemm_bt<1><<<512,  256, 0, stream>>>(fb, w2T, b2 + l * 1024, x, nullptr, nullptr, 1024, 4096, 8);
    }
    transpose_k<<<dim3(8, 32), tb, 0, stream>>>(Wh, whT, 1024, 256);
    ln_k<<<8192, 256, 0, stream>>>(x, lnfg, lnfb, h);
    gemm_bt<3><<<128, 256, 0, stream>>>(h, whT, bh, nullptr, nullptr, (float*)d_out, 256, 1024, 2);
}